// Round 10
// baseline (400.546 us; speedup 1.0000x reference)
//
#include <hip/hip_runtime.h>
#include <cstdint>

typedef unsigned short u16;
typedef unsigned int u32;
typedef unsigned long long u64;
typedef __attribute__((ext_vector_type(4))) float f32x4;
typedef __attribute__((ext_vector_type(16))) float f32x16;
typedef __attribute__((ext_vector_type(8))) __bf16 bf16x8;
typedef __attribute__((ext_vector_type(8))) u16 u16x8;
typedef __attribute__((ext_vector_type(4))) u32 u32x4;
typedef __attribute__((ext_vector_type(2))) int i32x2;

#define DEV __device__ __forceinline__

DEV u16 cvt16(float f) {
  __bf16 h = (__bf16)f;
  return __builtin_bit_cast(u16, h);
}
DEV u16 f2bf(float f) {  // round-to-nearest-even (for host-data convert)
  u32 u = __builtin_bit_cast(u32, f);
  u += 0x7fffu + ((u >> 16) & 1u);
  return (u16)(u >> 16);
}
DEV float bflo2f(u32 packed) { return __builtin_bit_cast(float, packed << 16); }
DEV float bfhi2f(u32 packed) { return __builtin_bit_cast(float, packed & 0xffff0000u); }

// async global->LDS, 16B per lane. lds pointer must be the WAVE-UNIFORM base;
// HW adds lane*16. Global pointer is per-lane.
DEV void g2l16(void* lds_wave_base, const void* gsrc) {
  __builtin_amdgcn_global_load_lds(
      (const __attribute__((address_space(1))) u32*)gsrc,
      (__attribute__((address_space(3))) u32*)lds_wave_base, 16, 0, 0);
}

DEV float gelu_tanh(float v) {
  float z = v * (0.7978845608f + 0.0356774081f * v * v);
  float e = __expf(2.0f * z);
  float th = 1.0f - 2.0f / (e + 1.0f);
  return 0.5f * v * (1.0f + th);
}

// ---------------- depthwise conv 3x3 (first 192 ch) + passthrough ----------
__global__ __launch_bounds__(256) void conv_k(const float* __restrict__ x,
                                              const float* __restrict__ cw,
                                              const float* __restrict__ cb,
                                              float* __restrict__ xc) {
  const int bc = blockIdx.x;             // b*384 + c
  const int c = bc % 384;
  const int p4 = threadIdx.x * 4;
  const float* xp = x + ((size_t)bc << 10);
  float* op = xc + ((size_t)bc << 10) + p4;
  if (c >= 192) {
    *(f32x4*)op = *(const f32x4*)(xp + p4);
    return;
  }
  const int hh = p4 >> 5, ww0 = p4 & 31;
  const float* wb = cw + c * 9;
  float b0 = cb[c];
  float a0 = b0, a1 = b0, a2 = b0, a3 = b0;
#pragma unroll
  for (int dy = 0; dy < 3; ++dy) {
    int y = hh + dy - 1;
    if ((unsigned)y < 32u) {
      const float* rp = xp + y * 32 + ww0;
      f32x4 m = *(const f32x4*)rp;
      float lft = (ww0 > 0) ? rp[-1] : 0.f;
      float rgt = (ww0 < 28) ? rp[4] : 0.f;
      float w0 = wb[dy * 3], w1 = wb[dy * 3 + 1], w2 = wb[dy * 3 + 2];
      a0 += lft * w0 + m[0] * w1 + m[1] * w2;
      a1 += m[0] * w0 + m[1] * w1 + m[2] * w2;
      a2 += m[1] * w0 + m[2] * w1 + m[3] * w2;
      a3 += m[2] * w0 + m[3] * w1 + rgt * w2;
    }
  }
  f32x4 r = {a0, a1, a2, a3};
  *(f32x4*)op = r;
}

// ---------------- fused f32 -> bf16 convert of the 4 weight mats -----------
__global__ __launch_bounds__(256) void cvt4_k(const float* __restrict__ s0,
                                              const float* __restrict__ s1,
                                              const float* __restrict__ s2,
                                              const float* __restrict__ s3,
                                              u16* __restrict__ d0,
                                              u16* __restrict__ d1,
                                              u16* __restrict__ d2,
                                              u16* __restrict__ d3) {
  int id = blockIdx.x * 256 + threadIdx.x;
  if (id < 442368) d0[id] = f2bf(s0[id]);
  else if (id < 589824) d1[id - 442368] = f2bf(s1[id - 442368]);
  else if (id < 1179648) d2[id - 589824] = f2bf(s2[id - 589824]);
  else if (id < 1769472) d3[id - 1179648] = f2bf(s3[id - 1179648]);
}

// ---------------- channel-LN (NCHW) + transpose to [token][C] bf16 ---------
__global__ __launch_bounds__(256) void ln_t_k(const float* __restrict__ X,
                                              const float* __restrict__ w,
                                              const float* __restrict__ bsh,
                                              u16* __restrict__ Y) {
  __shared__ float tile[384][33];
  __shared__ float ps[8][32], ps2[8][32];
  __shared__ float mean_s[32], rstd_s[32];
  const int b = blockIdx.y;
  const int p0 = blockIdx.x * 32;
  const int t = threadIdx.x;
  const int pl = t & 31, cg = t >> 5;
  const float* xb = X + (((size_t)b * 384) << 10) + p0 + pl;
  float s = 0.f, s2 = 0.f;
  for (int c = cg; c < 384; c += 8) {
    float v = xb[(size_t)c << 10];
    tile[c][pl] = v;
    s += v;
    s2 += v * v;
  }
  ps[cg][pl] = s;
  ps2[cg][pl] = s2;
  __syncthreads();
  if (t < 32) {
    float a = 0.f, a2 = 0.f;
#pragma unroll
    for (int g = 0; g < 8; ++g) { a += ps[g][t]; a2 += ps2[g][t]; }
    float mu = a * (1.f / 384.f);
    float var = a2 * (1.f / 384.f) - mu * mu;
    mean_s[t] = mu;
    rstd_s[t] = rsqrtf(var + 1e-6f);
  }
  __syncthreads();
  const int cl = t & 63, pg = t >> 6;
  for (int p = pg; p < 32; p += 4) {
    float mu = mean_s[p], rs = rstd_s[p];
    size_t orow = (((size_t)b << 10) + p0 + p) * 384;
#pragma unroll
    for (int cc = 0; cc < 6; ++cc) {
      int c = cc * 64 + cl;
      float v = (tile[c][p] - mu) * rs * w[c] + bsh[c];
      Y[orow + c] = f2bf(v);
    }
  }
}

// ---------------- L2-normalize k heads in QKV rows (q folded into attn) ----
__global__ __launch_bounds__(256) void normk_k(u16* __restrict__ QKV) {
  const int t = threadIdx.x;
  const int w = t >> 6, l = t & 63;
  const int rg = l >> 4, li = l & 15;
  const int tok = blockIdx.x * 16 + w * 4 + rg;
  u16* rowp = QKV + (size_t)tok * 1152 + 384;
#pragma unroll
  for (int h = 0; h < 4; ++h) {
    u16* p = rowp + h * 96 + li * 6;
    u32 a = *(const u32*)p;
    u32 b2 = *(const u32*)(p + 2);
    u32 c = *(const u32*)(p + 4);
    float v[6] = {bflo2f(a), bfhi2f(a), bflo2f(b2), bfhi2f(b2), bflo2f(c), bfhi2f(c)};
    float ss = 0.f;
#pragma unroll
    for (int i = 0; i < 6; ++i) ss += v[i] * v[i];
#pragma unroll
    for (int mk = 1; mk < 16; mk <<= 1) ss += __shfl_xor(ss, mk, 64);
    float sc = 1.0f / fmaxf(sqrtf(ss), 1e-12f);
    u32 o0 = (u32)f2bf(v[0] * sc) | ((u32)f2bf(v[1] * sc) << 16);
    u32 o1 = (u32)f2bf(v[2] * sc) | ((u32)f2bf(v[3] * sc) << 16);
    u32 o2 = (u32)f2bf(v[4] * sc) | ((u32)f2bf(v[5] * sc) << 16);
    *(u32*)p = o0;
    *(u32*)(p + 2) = o1;
    *(u32*)(p + 4) = o2;
  }
}

// ---------------- flash attention v9: 32x32 MFMA, in-register P ------------
// (unchanged from round 9 — validated)
__global__ __launch_bounds__(256, 3) void attn_k(const u16* __restrict__ QKV,
                                                 const u16* __restrict__ Vg,
                                                 u16* __restrict__ O,
                                                 const float* __restrict__ temp) {
  __shared__ u16 Kt[2][6656];    // 64 rows × 104 u16, 13312B each
  __shared__ u16 Vt[2][6144];    // 96 rows × 64 u16 XOR-swz, 12288B each
  const int t = threadIdx.x;
  const int w = t >> 6, l = t & 63;
  const int l31 = l & 31, hi = l >> 5;
  const int id = blockIdx.x;
  const int xcd = id & 7, jj = id >> 3;          // jj in [0,128)
  const int bh = xcd * 16 + (jj >> 3);
  const int qb = jj & 7;
  const int b = bh >> 2, h = bh & 3;
  const int q0 = qb * 128 + w * 32;
  const u16* Qb = QKV + (size_t)b * 1024 * 1152;
  const char* Kbg = (const char*)QKV + (size_t)b * 1024 * 2304 + 768 + 192 * h;
  const char* Vbg = (const char*)(Vg + (size_t)bh * 98304);  // [96][1024]
  const float tl2e = temp[h] * 1.44269504f;
  const float mT2 = -fabsf(temp[h]) * 1.44269504f;

  u32 kOff[4], vOff[3];
#pragma unroll
  for (int i = 0; i < 4; ++i) {
    int s = (i < 3) ? (i * 256 + t) : (768 + w * 16 + (l & 15));
    int row = s / 13, c = s - row * 13;
    kOff[i] = row * 2304 + ((c < 12) ? c * 16 : 0);
  }
#pragma unroll
  for (int i = 0; i < 3; ++i) {
    int s = i * 256 + t;
    int row = s >> 3, cb = (s & 7) * 16;
    vOff[i] = row * 2048 + (cb ^ ((row & 7) << 4));
  }

  bf16x8 qf[6];
  {
    const u16* qp = Qb + (size_t)(q0 + l31) * 1152 + h * 96 + hi * 8;
#pragma unroll
    for (int kc = 0; kc < 6; ++kc) qf[kc] = *(const bf16x8*)(qp + kc * 16);
  }
  float alpha;
  {
    float ss = 0.f;
#pragma unroll
    for (int kc = 0; kc < 6; ++kc)
#pragma unroll
      for (int e = 0; e < 8; ++e) {
        float v = (float)qf[kc][e];
        ss += v * v;
      }
    ss += __shfl_xor(ss, 32, 64);
    alpha = tl2e * rsqrtf(fmaxf(ss, 1e-24f));
  }

  f32x16 oa[3];
#pragma unroll
  for (int dt = 0; dt < 3; ++dt)
#pragma unroll
    for (int r = 0; r < 16; ++r) oa[dt][r] = 0.f;
  float l_r = 0.f;

#define STAGE(buf, kv0)                                                        \
  {                                                                            \
    const char* kb = Kbg + (size_t)(kv0) * 2304;                               \
    const char* vb = Vbg + (size_t)(kv0) * 2;                                  \
    char* kd = (char*)&Kt[buf][0];                                             \
    char* vd = (char*)&Vt[buf][0];                                             \
    g2l16(kd + w * 1024, kb + kOff[0]);                                        \
    g2l16(kd + 4096 + w * 1024, kb + kOff[1]);                                 \
    g2l16(kd + 8192 + w * 1024, kb + kOff[2]);                                 \
    if (l < 16) g2l16(kd + 12288 + w * 256, kb + kOff[3]);                     \
    g2l16(vd + w * 1024, vb + vOff[0]);                                        \
    g2l16(vd + 4096 + w * 1024, vb + vOff[1]);                                 \
    g2l16(vd + 8192 + w * 1024, vb + vOff[2]);                                 \
  }

  STAGE(0, 0);
  for (int tt = 0; tt < 16; ++tt) {
    const int cur = tt & 1;
    if (tt < 15) {
      STAGE(cur ^ 1, (tt + 1) * 64);
      asm volatile("s_waitcnt vmcnt(7)" ::: "memory");
    } else {
      asm volatile("s_waitcnt vmcnt(0)" ::: "memory");
    }
    __builtin_amdgcn_s_barrier();
    const char* Kc = (const char*)&Kt[cur][0];
    const char* Vc = (const char*)&Vt[cur][0];
    f32x16 st[2];
#pragma unroll
    for (int n = 0; n < 2; ++n)
#pragma unroll
      for (int r = 0; r < 16; ++r) st[n][r] = 0.f;
#pragma unroll
    for (int n = 0; n < 2; ++n) {
      const char* krow = Kc + (n * 32 + l31) * 208 + hi * 16;
#pragma unroll
      for (int kc = 0; kc < 6; ++kc) {
        bf16x8 kf = *(const bf16x8*)(krow + kc * 32);
        st[n] = __builtin_amdgcn_mfma_f32_32x32x16_bf16(kf, qf[kc], st[n], 0, 0, 0);
      }
    }
    u32 pk[2][8];
#pragma unroll
    for (int n = 0; n < 2; ++n) {
      float p[16];
#pragma unroll
      for (int r = 0; r < 16; ++r) {
        p[r] = exp2f(fmaf(st[n][r], alpha, mT2));
        l_r += p[r];
      }
#pragma unroll
      for (int m = 0; m < 8; ++m)
        pk[n][m] = (u32)cvt16(p[2 * m]) | ((u32)cvt16(p[2 * m + 1]) << 16);
    }
#pragma unroll
    for (int c = 0; c < 4; ++c) {
      const int n = c >> 1, cc = c & 1;
      i32x2 s1 = __builtin_amdgcn_permlane32_swap((int)pk[n][4 * cc],
                                                  (int)pk[n][4 * cc + 2], 0, 0);
      i32x2 s2 = __builtin_amdgcn_permlane32_swap((int)pk[n][4 * cc + 1],
                                                  (int)pk[n][4 * cc + 3], 0, 0);
      u32x4 wd;
      wd[0] = (u32)s1[0]; wd[1] = (u32)s2[0];
      wd[2] = (u32)s1[1]; wd[3] = (u32)s2[1];
      bf16x8 pa = __builtin_bit_cast(bf16x8, wd);
      const u32 vcol = (u32)((c * 32 + hi * 16) ^ ((l31 & 7) << 4));
#pragma unroll
      for (int dt = 0; dt < 3; ++dt) {
        bf16x8 vf = *(const bf16x8*)(Vc + (dt * 32 + l31) * 128 + vcol);
        oa[dt] = __builtin_amdgcn_mfma_f32_32x32x16_bf16(pa, vf, oa[dt], 0, 0, 0);
      }
    }
    __builtin_amdgcn_s_barrier();
  }
#undef STAGE
  l_r += __shfl_xor(l_r, 32, 64);
  float inv = 1.0f / l_r;
#pragma unroll
  for (int r = 0; r < 16; ++r) {
    const int qr = (r & 3) + 8 * (r >> 2) + 4 * hi;
    float invr = __shfl(inv, qr, 64);
    const int tok = q0 + qr;
    u16* orow = O + ((size_t)b * 1024 + tok) * 384 + h * 96;
#pragma unroll
    for (int dt = 0; dt < 3; ++dt)
      orow[dt * 32 + l31] = f2bf(oa[dt][r] * invr);
  }
}

// ---------------- 256x128 bf16 GEMM, depth-3 pipelined ---------------------
// A [M][K] rm bf16 (M=32768), B [N][K] rm bf16, D = A @ B^T.
// 3 LDS buffers; at iter k stage tile k+2, wait vmcnt(6) -> tile k landed
// (issued 2 iters ago: ~2 iterations of latency hiding).
// EPI 1: gelu(D+bias) -> bf16 rm [M][N] (LDS-bounce, 2 passes)
// EPI 4: QKV: cols<768 -> rm [tok][1152]; cols>=768 -> Vt [bh][96][n] (vtp)
template <int EPI>
__global__ __launch_bounds__(512) void gemm256_k(const u16* __restrict__ A,
                                                 const u16* __restrict__ B,
                                                 int N, int K,
                                                 const float* __restrict__ bias,
                                                 u16* __restrict__ vtp,
                                                 u16* __restrict__ outp,
                                                 int nbx) {
  __shared__ u16 SM[36864];      // 72KB: A bufs 3×16KB | B bufs 3×8KB
  const int t = threadIdx.x;
  const int w = t >> 6, l = t & 63;
  const int l15 = l & 15, kg = l >> 4;
  const int id = blockIdx.x;
  const int xcd = id & 7, jj = id >> 3;
  const int qq = jj / nbx;
  const int bx = jj - qq * nbx;
  const int by = xcd * 16 + qq;
  const int m0 = by * 256, n0 = bx * 128;
  const int wr = w >> 1, wc = w & 1;
  const size_t ldab = (size_t)K * 2;
  const char* pa1 = (const char*)A + (size_t)(m0 + (t >> 2)) * ldab + (t & 3) * 16;
  const char* pa2 = pa1 + (size_t)128 * ldab;
  const char* pb1 = (const char*)B + (size_t)(n0 + (t >> 2)) * ldab + (t & 3) * 16;
  char* SMc = (char*)SM;

  f32x4 acc[4][4];
#pragma unroll
  for (int m = 0; m < 4; ++m)
#pragma unroll
    for (int n = 0; n < 4; ++n) acc[m][n] = {0.f, 0.f, 0.f, 0.f};

#define GSTAGE(bf, kti)                                                        \
  {                                                                            \
    const size_t o = (size_t)(kti) * 64;                                       \
    g2l16(SMc + (bf) * 16384 + w * 1024, pa1 + o);                             \
    g2l16(SMc + (bf) * 16384 + 8192 + w * 1024, pa2 + o);                      \
    g2l16(SMc + 49152 + (bf) * 8192 + w * 1024, pb1 + o);                      \
  }

  const int nkt = K >> 5;
  GSTAGE(0, 0);
  GSTAGE(1, 1);
  for (int kt = 0; kt < nkt; ++kt) {
    const int buf = kt % 3;
    if (kt + 2 < nkt) {
      GSTAGE((kt + 2) % 3, kt + 2);
      asm volatile("s_waitcnt vmcnt(6)" ::: "memory");
    } else if (kt + 1 < nkt) {
      asm volatile("s_waitcnt vmcnt(3)" ::: "memory");
    } else {
      asm volatile("s_waitcnt vmcnt(0)" ::: "memory");
    }
    __builtin_amdgcn_s_barrier();
    __builtin_amdgcn_sched_barrier(0);
    const u16* Ab = SM + buf * 8192;
    const u16* Bb = SM + 24576 + buf * 4096;
    bf16x8 af[4], bfr[4];
#pragma unroll
    for (int m = 0; m < 4; ++m)
      af[m] = *(const bf16x8*)(Ab + (wr * 64 + m * 16 + l15) * 32 + kg * 8);
#pragma unroll
    for (int n = 0; n < 4; ++n)
      bfr[n] = *(const bf16x8*)(Bb + (wc * 64 + n * 16 + l15) * 32 + kg * 8);
    __builtin_amdgcn_s_setprio(1);
#pragma unroll
    for (int m = 0; m < 4; ++m)
#pragma unroll
      for (int n = 0; n < 4; ++n)
        acc[m][n] = __builtin_amdgcn_mfma_f32_16x16x32_bf16(af[m], bfr[n], acc[m][n], 0, 0, 0);
    __builtin_amdgcn_s_setprio(0);
    __builtin_amdgcn_sched_barrier(0);
    __builtin_amdgcn_s_barrier();
  }
#undef GSTAGE

  if (EPI == 4 && n0 >= 768) {   // V section: transposed u64 into vtp
#pragma unroll
    for (int m = 0; m < 4; ++m) {
      const int tokbase = m0 + wr * 64 + m * 16 + kg * 4;
      const int bb = tokbase >> 10, nb = tokbase & 1023;
#pragma unroll
      for (int n = 0; n < 4; ++n) {
        int within = n0 - 768 + wc * 64 + n * 16 + l15;
        int hh = within / 96;
        int dd = within - hh * 96;
        float bs = bias[768 + within];
        int bh = bb * 4 + hh;
        u64 pk = 0;
#pragma unroll
        for (int j = 0; j < 4; ++j)
          pk |= (u64)cvt16(acc[m][n][j] + bs) << (16 * j);
        *(u64*)(vtp + ((size_t)bh * 96 + dd) * 1024 + nb) = pk;
      }
    }
    return;
  }

  // ---- LDS-bounce epilogue, two 128-row passes (Ct overlays A bufs 0-1) ----
  u16* Ct = SM;                  // 128x128 u16 (32KB)
  float bs[4];
#pragma unroll
  for (int n = 0; n < 4; ++n) bs[n] = bias[n0 + wc * 64 + n * 16 + l15];
  const size_t ostride = (EPI == 4) ? 1152 : (size_t)N;
#pragma unroll
  for (int p = 0; p < 2; ++p) {
    if ((wr >> 1) == p) {
      u16* cw_ = Ct + ((wr & 1) * 64 + kg * 4) * 128 + wc * 64 + l15;
#pragma unroll
      for (int m = 0; m < 4; ++m)
#pragma unroll
        for (int n = 0; n < 4; ++n)
#pragma unroll
          for (int j = 0; j < 4; ++j) {
            float v = acc[m][n][j] + bs[n];
            if (EPI == 1) v = gelu_tanh(v);
            cw_[(m * 16 + j) * 128 + n * 16] = cvt16(v);
          }
    }
    __syncthreads();
    const int row_l = t >> 2;
    const int colc = (t & 3) * 32;
    const u16* src = Ct + row_l * 128 + colc;
    u16* dst = outp + (size_t)(m0 + p * 128 + row_l) * ostride + n0 + colc;
#pragma unroll
    for (int c4 = 0; c4 < 4; ++c4)
      *(u16x8*)(dst + c4 * 8) = *(const u16x8*)(src + c4 * 8);
    __syncthreads();
  }
}

// ---------------- 128x128 bf16 GEMM (EPI2), depth-3 pipelined --------------
// SWZ 2: 768 blocks; 3 by-blocks of one bx co-located per XCD.
__global__ __launch_bounds__(256) void gemm_k(const u16* __restrict__ A,
                                              const u16* __restrict__ B,
                                              int K,
                                              const float* __restrict__ bias,
                                              const float* __restrict__ gamma,
                                              const float* __restrict__ res,
                                              float* __restrict__ outp) {
  __shared__ u16 SM[24576];      // 48KB: A bufs 3×8KB | B bufs 3×8KB
  const int t = threadIdx.x;
  const int w = t >> 6, l = t & 63;
  const int l15 = l & 15, kg = l >> 4;
  int id = blockIdx.x;
  int xcd = id & 7, jj = id >> 3;
  int by = jj % 3;
  int bx = (jj / 3) * 8 + xcd;
  const int m0 = by * 128, n0 = bx * 128;
  const int wr = w >> 1, wc = w & 1;

  const size_t ldab = (size_t)K * 2;
  const char* pa1 = (const char*)A + (size_t)(m0 + (t >> 2)) * ldab + (t & 3) * 16;
  const char* pa2 = pa1 + (size_t)64 * ldab;
  const char* pb1 = (const char*)B + (size_t)(n0 + (t >> 2)) * ldab + (t & 3) * 16;
  const char* pb2 = pb1 + (size_t)64 * ldab;
  char* SMc = (char*)SM;

  f32x4 acc[4][4];
#pragma unroll
  for (int m = 0; m < 4; ++m)
#pragma unroll
    for (int n = 0; n < 4; ++n) acc[m][n] = {0.f, 0.f, 0.f, 0.f};

#define KSTAGE(bf, kti)                                                        \
  {                                                                            \
    const size_t o = (size_t)(kti) * 64;                                       \
    char* ad = SMc + (bf) * 8192 + w * 1024;                                   \
    char* bd = SMc + 24576 + (bf) * 8192 + w * 1024;                           \
    g2l16(ad, pa1 + o); g2l16(ad + 4096, pa2 + o);                             \
    g2l16(bd, pb1 + o); g2l16(bd + 4096, pb2 + o);                             \
  }

  const int nkt = K >> 5;
  KSTAGE(0, 0);
  KSTAGE(1, 1);
  for (int kt = 0; kt < nkt; ++kt) {
    const int buf = kt % 3;
    if (kt + 2 < nkt) {
      KSTAGE((kt + 2) % 3, kt + 2);
      asm volatile("s_waitcnt vmcnt(8)" ::: "memory");
    } else if (kt + 1 < nkt) {
      asm volatile("s_waitcnt vmcnt(4)" ::: "memory");
    } else {
      asm volatile("s_waitcnt vmcnt(0)" ::: "memory");
    }
    __builtin_amdgcn_s_barrier();
    __builtin_amdgcn_sched_barrier(0);
    const u16* Ab = SM + buf * 4096;
    const u16* Bb = SM + 12288 + buf * 4096;
    bf16x8 af[4], bfr[4];
#pragma unroll
    for (int m = 0; m < 4; ++m)
      af[m] = *(const bf16x8*)(Ab + (wr * 64 + m * 16 + l15) * 32 + kg * 8);
#pragma unroll
    for (int n = 0; n < 4; ++n)
      bfr[n] = *(const bf16x8*)(Bb + (wc * 64 + n * 16 + l15) * 32 + kg * 8);
    __builtin_amdgcn_s_setprio(1);
#pragma unroll
    for (int m = 0; m < 4; ++m)
#pragma unroll
      for (int n = 0; n < 4; ++n)
        acc[m][n] = __builtin_amdgcn_mfma_f32_16x16x32_bf16(af[m], bfr[n], acc[m][n], 0, 0, 0);
    __builtin_amdgcn_s_setprio(0);
    __builtin_amdgcn_sched_barrier(0);
    __builtin_amdgcn_s_barrier();
  }
#undef KSTAGE

  // EPI2: rows=channels, cols=tokens; out[b,c,p] = res + gamma[c]*(D+bias[c])
#pragma unroll
  for (int m = 0; m < 4; ++m) {
#pragma unroll
    for (int n = 0; n < 4; ++n) {
      int tok = n0 + wc * 64 + n * 16 + l15;
      int bb = tok >> 10, p = tok & 1023;
#pragma unroll
      for (int j = 0; j < 4; ++j) {
        int c = m0 + wr * 64 + m * 16 + kg * 4 + j;
        size_t addr = (((size_t)(bb * 384 + c)) << 10) + p;
        outp[addr] = res[addr] + gamma[c] * (acc[m][n][j] + bias[c]);
      }
    }
  }
}

// ---------------------------------------------------------------------------
extern "C" void kernel_launch(void* const* d_in, const int* in_sizes, int n_in,
                              void* d_out, int out_size, void* d_ws,
                              size_t ws_size, hipStream_t stream) {
  const float* x      = (const float*)d_in[0];
  const float* conv_w = (const float*)d_in[1];
  const float* conv_b = (const float*)d_in[2];
  const float* nxca_w = (const float*)d_in[3];
  const float* nxca_b = (const float*)d_in[4];
  const float* temp   = (const float*)d_in[5];
  const float* qkv_w  = (const float*)d_in[6];
  const float* qkv_b  = (const float*)d_in[7];
  const float* proj_w = (const float*)d_in[8];
  const float* proj_b = (const float*)d_in[9];
  const float* norm_w = (const float*)d_in[10];
  const float* norm_b = (const float*)d_in[11];
  const float* fc1_w  = (const float*)d_in[12];
  const float* fc1_b  = (const float*)d_in[13];
  const float* fc2_w  = (const float*)d_in[14];
  const float* fc2_b  = (const float*)d_in[15];
  const float* g_xca  = (const float*)d_in[16];
  const float* g_mlp  = (const float*)d_in[17];
  (void)in_sizes; (void)n_in; (void)out_size; (void)ws_size;

  char* ws = (char*)d_ws;
  float* xc  = (float*)(ws);                    // 50,331,648 B (f32 NCHW, shortcut)
  u16* Y     = (u16*)(ws + 50331648);           // 25,165,824 B (also Obuf)
  u16* QKVr  = (u16*)(ws + 75497472);           // 75,497,472 B  [32768][1152]
  u16* Vt    = (u16*)(ws + 150994944);          // 25,165,824 B  [bh][96][1024]
  u16* Obuf  = Y;                               // attn O overlays Y (dead then)
  u16* H1    = QKVr;                            // fc1 out overlays QKVr+Vt
  u16* wq    = (u16*)(ws + 176160768);
  u16* wp    = (u16*)(ws + 177045504);
  u16* w1    = (u16*)(ws + 177340416);
  u16* w2    = (u16*)(ws + 178520064);          // end: 179,699,712 B

  cvt4_k<<<6912, 256, 0, stream>>>(qkv_w, proj_w, fc1_w, fc2_w, wq, wp, w1, w2);

  conv_k<<<12288, 256, 0, stream>>>(x, conv_w, conv_b, xc);
  ln_t_k<<<dim3(32, 32), 256, 0, stream>>>(xc, nxca_w, nxca_b, Y);
  gemm256_k<4><<<1152, 512, 0, stream>>>(Y, wq, 1152, 384, qkv_b, Vt, QKVr, 9);
  normk_k<<<2048, 256, 0, stream>>>(QKVr);
  attn_k<<<1024, 256, 0, stream>>>(QKVr, Vt, Obuf, temp);
  gemm_k<<<768, 256, 0, stream>>>(wp, Obuf, 384, proj_b, g_xca, xc, xc);
  ln_t_k<<<dim3(32, 32), 256, 0, stream>>>(xc, norm_w, norm_b, Y);
  gemm256_k<1><<<1536, 512, 0, stream>>>(Y, w1, 1536, 384, fc1_b, nullptr, H1, 12);
  gemm_k<<<768, 256, 0, stream>>>(w2, H1, 1536, fc2_b, g_mlp, xc, (float*)d_out);
}